// Round 3
// baseline (197.512 us; speedup 1.0000x reference)
//
#include <hip/hip_runtime.h>

typedef unsigned short u16;
typedef __fp16 halfx2 __attribute__((ext_vector_type(2)));
typedef __fp16 halfx8 __attribute__((ext_vector_type(8)));
typedef float floatx4 __attribute__((ext_vector_type(4)));
typedef unsigned short u16x4 __attribute__((ext_vector_type(4)));
typedef unsigned short u16x8 __attribute__((ext_vector_type(8)));

#define D_MODEL 768
#define NH 12
#define DH 64
#define SEQ 2048
#define BATCH 2
#define MTOK 4096            // BATCH*SEQ
#define DQKV 2304

__device__ __forceinline__ u16 f2h(float f) {
    __fp16 h = (__fp16)f;
    return __builtin_bit_cast(u16, h);
}

__device__ __forceinline__ void gload_lds16(const void* g, void* l) {
    __builtin_amdgcn_global_load_lds(
        (const __attribute__((address_space(1))) void*)g,
        (__attribute__((address_space(3))) void*)l, 16, 0, 0);
}

// ---------------- prep: W transposes -> f16 [n][k] (576 blocks) + x -> f16 cast (1536 blocks) ----------------

__global__ __launch_bounds__(256) void wprep_kernel(const float* __restrict__ Wq, const float* __restrict__ Wk,
                                                    const float* __restrict__ Wv, const float* __restrict__ Wo,
                                                    const float* __restrict__ x,
                                                    u16* __restrict__ WqkvT, u16* __restrict__ WoT,
                                                    u16* __restrict__ xh) {
    __shared__ u16 t[64][72];
    int bid = blockIdx.x;
    int tid = threadIdx.x;
    if (bid >= 576) {
        // x fp32 -> f16, 2048 elems per block
        int idx = (bid - 576) * 2048 + tid * 8;
        float4 v0 = *(const float4*)(x + idx);
        float4 v1 = *(const float4*)(x + idx + 4);
        union { u16x8 u; halfx2 h[4]; } pk;
        pk.h[0] = __builtin_amdgcn_cvt_pkrtz(v0.x, v0.y);
        pk.h[1] = __builtin_amdgcn_cvt_pkrtz(v0.z, v0.w);
        pk.h[2] = __builtin_amdgcn_cvt_pkrtz(v1.x, v1.y);
        pk.h[3] = __builtin_amdgcn_cvt_pkrtz(v1.z, v1.w);
        *(u16x8*)(xh + idx) = pk.u;
        return;
    }
    int z = bid / 144;
    int t2 = bid % 144;
    int k0 = (t2 / 12) * 64, n0 = (t2 % 12) * 64;
    const float* W = (z == 0) ? Wq : (z == 1) ? Wk : (z == 2) ? Wv : Wo;
    u16* dst = (z < 3) ? (WqkvT + (size_t)z * 768 * 768) : WoT;
#pragma unroll
    for (int p = 0; p < 16; ++p) {
        int idx = p * 256 + tid;
        int kr = idx >> 6, nc = idx & 63;
        t[kr][nc] = f2h(W[(size_t)(k0 + kr) * 768 + n0 + nc]);
    }
    __syncthreads();
#pragma unroll
    for (int p = 0; p < 16; ++p) {
        int idx = p * 256 + tid;
        int nr = idx >> 6, kc = idx & 63;
        dst[(size_t)(n0 + nr) * 768 + k0 + kc] = t[kc][nr];
    }
}

// ---------------- QKV GEMM, A staged from pre-cast f16 xh via global_load_lds ----------------
// 64x128 tile (1152 blocks), BK=64. Epilogue: Q -> qP[bh][s][64] pre-scaled by
// 0.125*log2e, K -> kP[bh][s][64], V -> vT[bh][d][s].

__global__ __launch_bounds__(256) void gemm_qkv(const u16* __restrict__ xh, const u16* __restrict__ Bt,
                                                const float* __restrict__ bq, const float* __restrict__ bk,
                                                const float* __restrict__ bv,
                                                u16* __restrict__ qP, u16* __restrict__ kP,
                                                u16* __restrict__ vTout) {
    const int tid = threadIdx.x;
    const int wid = tid >> 6;
    const int lane = tid & 63;
    const int qd = lane >> 4;
    const int l15 = lane & 15;

    const int tn = blockIdx.x * 128;   // 18 n-tiles
    const int tm = blockIdx.y * 64;    // 64 m-tiles
    const int wm = (wid >> 1) * 32;
    const int wn = (wid & 1) * 64;

    __shared__ alignas(16) u16 As[64 * 64];    // 8 KB
    __shared__ alignas(16) u16 Bs[128 * 64];   // 16 KB

    floatx4 acc[2][4];
#pragma unroll
    for (int i = 0; i < 2; ++i)
#pragma unroll
        for (int j = 0; j < 4; ++j) acc[i][j] = (floatx4)(0.0f);

    const u16* Ag[2];
#pragma unroll
    for (int rd = 0; rd < 2; ++rd) {
        int s = rd * 256 + tid;
        int r = s >> 3, bl = (s & 7) ^ (r & 7);
        Ag[rd] = xh + (size_t)(tm + r) * 768 + bl * 8;
    }
    const u16* Bg[4];
#pragma unroll
    for (int rd = 0; rd < 4; ++rd) {
        int s = rd * 256 + tid;
        int r = s >> 3, bl = (s & 7) ^ (r & 7);
        Bg[rd] = Bt + (size_t)(tn + r) * 768 + bl * 8;
    }

    for (int kb = 0; kb < 768; kb += 64) {
        __syncthreads();
#pragma unroll
        for (int rd = 0; rd < 2; ++rd)
            gload_lds16(Ag[rd] + kb, As + (size_t)(rd * 256 + tid) * 8);
#pragma unroll
        for (int rd = 0; rd < 4; ++rd)
            gload_lds16(Bg[rd] + kb, Bs + (size_t)(rd * 256 + tid) * 8);
        __syncthreads();

#pragma unroll
        for (int ks = 0; ks < 2; ++ks) {
            halfx8 af[2], bf[4];
#pragma unroll
            for (int i = 0; i < 2; ++i) {
                int r = wm + i * 16 + l15;
                af[i] = *(const halfx8*)(As + r * 64 + (((ks * 4 + qd) ^ (r & 7)) * 8));
            }
#pragma unroll
            for (int j = 0; j < 4; ++j) {
                int r2 = wn + j * 16 + l15;
                bf[j] = *(const halfx8*)(Bs + r2 * 64 + (((ks * 4 + qd) ^ (r2 & 7)) * 8));
            }
#pragma unroll
            for (int i = 0; i < 2; ++i)
#pragma unroll
                for (int j = 0; j < 4; ++j)
                    acc[i][j] = __builtin_amdgcn_mfma_f32_16x16x32_f16(af[i], bf[j], acc[i][j], 0, 0, 0);
        }
    }

    const float cscale = 0.125f * 1.44269504088896340736f;
    const int rgn = (tn < 768) ? 0 : (tn < 1536) ? 1 : 2;   // block-uniform
    const float* bsrc = (rgn == 0) ? bq : (rgn == 1) ? bk : bv;
#pragma unroll
    for (int j = 0; j < 4; ++j) {
        int col = tn + wn + j * 16 + l15;
        int cl = col - rgn * 768;
        float bvv = bsrc[cl];
        int h = cl >> 6, d = cl & 63;
#pragma unroll
        for (int i = 0; i < 2; ++i) {
            int row0 = tm + wm + i * 16 + qd * 4;
            int b = row0 >> 11, s0 = row0 & 2047;
            u16x4 pk;
#pragma unroll
            for (int r = 0; r < 4; ++r) {
                float v = acc[i][j][r] + bvv;
                if (rgn == 0) v *= cscale;
                pk[r] = f2h(v);
            }
            if (rgn == 2) {
                *(u16x4*)(vTout + ((size_t)(b * NH + h) * 64 + d) * SEQ + s0) = pk;
            } else {
                u16* dst = (rgn == 0) ? qP : kP;
#pragma unroll
                for (int r = 0; r < 4; ++r)
                    dst[((size_t)(b * NH + h) * SEQ + s0 + r) * DH + d] = pk[r];
            }
        }
    }
}

// ---------------- attention R14: register diet -> 3 blocks/CU, single generation ----------------
// grid = (24 bh, 32 q-tiles of 64) = 768 blocks at 3/CU (was 2/CU + a half-empty
// tail generation). Cuts vs R13 (~210 -> ~160 unified regs):
//   1. Q fragments in shared LDS (all 4 waves use identical fragments) -> -32
//   2. single sc buffer: exp(t) per-tile immediately followed by QK(t+1)
//      overwrite of the same regs -> -32
//   3. lsum as 4 scalar VALU accumulators (folded into exp) + one shfl_xor
//      pair at the end; V single-buffer loaded same iter (slack = exp+QK) -> -32
// launch_bounds(256,3) forces the allocator to the 170-reg budget.

__global__ __launch_bounds__(256, 3) void attn_kernel(const u16* __restrict__ qP, const u16* __restrict__ kP,
                                                      const u16* __restrict__ vT, u16* __restrict__ attn) {
    const int tid = threadIdx.x;
    const int wid = tid >> 6;
    const int lane = tid & 63;
    const int qd = lane >> 4;
    const int l15 = lane & 15;

    const int bh = blockIdx.x;
    const int b = bh / NH, h = bh % NH;
    const int q0 = blockIdx.y * 64;

    // LDS: Q fragments [ks 2][jn 4][lane 64] halfx8 = 8192 B, then per-wave
    // P [64][36] u16 = 4608 B each. Total 26624 B (3 blocks/CU = 80 KB).
    __shared__ alignas(16) u16 smem[13312];
    u16* qlds = smem;                        // 4096 u16
    u16* ps = smem + 4096 + wid * 2304;

    // stage Q fragments: wave wid stores jn = wid (fragments are lane-indexed,
    // identical across waves)
#pragma unroll
    for (int ks = 0; ks < 2; ++ks) {
        halfx8 qv = *(const halfx8*)(qP + (size_t)(bh * SEQ + q0 + wid * 16 + l15) * DH + ks * 32 + qd * 8);
        *(halfx8*)(qlds + (size_t)((ks * 4 + wid) * 64 + lane) * 8) = qv;
    }
    __syncthreads();

    auto AQ = [&](int jn, int ks) -> halfx8 {
        return *(const halfx8*)(qlds + (size_t)((ks * 4 + jn) * 64 + lane) * 8);
    };

    floatx4 o[4][4];
#pragma unroll
    for (int ip = 0; ip < 4; ++ip)
#pragma unroll
        for (int jn = 0; jn < 4; ++jn) o[ip][jn] = (floatx4)(0.0f);
    float lsum[4] = {0.0f, 0.0f, 0.0f, 0.0f};

    const u16* kbase = kP + (size_t)(bh * SEQ + wid * 32 + l15) * DH + qd * 8;
    const u16* vbase = vT + (size_t)(bh * 64 + l15) * SEQ + wid * 32 + qd * 8;

    // prologue: sc(0) = QK(0)
    floatx4 sc[2][4];
    {
        halfx8 ak0[2][2];
#pragma unroll
        for (int mi = 0; mi < 2; ++mi)
#pragma unroll
            for (int ks = 0; ks < 2; ++ks)
                ak0[mi][ks] = *(const halfx8*)(kbase + (size_t)(mi * 16) * DH + ks * 32);
#pragma unroll
        for (int jn = 0; jn < 4; ++jn) {
            halfx8 a0 = AQ(jn, 0), a1 = AQ(jn, 1);
#pragma unroll
            for (int mi = 0; mi < 2; ++mi) {
                floatx4 z = (floatx4)(0.0f);
                z = __builtin_amdgcn_mfma_f32_16x16x32_f16(ak0[mi][0], a0, z, 0, 0, 0);
                sc[mi][jn] = __builtin_amdgcn_mfma_f32_16x16x32_f16(ak0[mi][1], a1, z, 0, 0, 0);
            }
        }
    }

    for (int kt = 0; kt < 16; ++kt) {
        const int kt1 = (kt + 1) & 15;   // wrap harmless (valid addresses, values unused)

        // issue K(t+1) and V(t) loads
        halfx8 akn[2][2];
#pragma unroll
        for (int mi = 0; mi < 2; ++mi)
#pragma unroll
            for (int ks = 0; ks < 2; ++ks)
                akn[mi][ks] = *(const halfx8*)(kbase + (size_t)(kt1 * 128 + mi * 16) * DH + ks * 32);
        halfx8 avc[4];
#pragma unroll
        for (int ip = 0; ip < 4; ++ip)
            avc[ip] = *(const halfx8*)(vbase + (size_t)(ip * 16) * SEQ + kt * 128);

        // exp(t): read sc, accumulate lsum on VALU, pack -> LDS. sc dead after.
#pragma unroll
        for (int mi = 0; mi < 2; ++mi)
#pragma unroll
            for (int jn = 0; jn < 4; ++jn) {
                float p0 = __builtin_amdgcn_exp2f(sc[mi][jn][0]);
                float p1 = __builtin_amdgcn_exp2f(sc[mi][jn][1]);
                float p2 = __builtin_amdgcn_exp2f(sc[mi][jn][2]);
                float p3 = __builtin_amdgcn_exp2f(sc[mi][jn][3]);
                lsum[jn] += (p0 + p1) + (p2 + p3);
                union { u16x4 u; halfx2 h[2]; } pk;
                pk.h[0] = __builtin_amdgcn_cvt_pkrtz(p0, p1);
                pk.h[1] = __builtin_amdgcn_cvt_pkrtz(p2, p3);
                *(u16x4*)(ps + (jn * 16 + l15) * 36 + mi * 16 + qd * 4) = pk.u;
            }

        // QK(t+1): overwrite sc in place (single buffer)
        __builtin_amdgcn_s_setprio(1);
#pragma unroll
        for (int jn = 0; jn < 4; ++jn) {
            halfx8 a0 = AQ(jn, 0), a1 = AQ(jn, 1);
#pragma unroll
            for (int mi = 0; mi < 2; ++mi) {
                floatx4 z = (floatx4)(0.0f);
                z = __builtin_amdgcn_mfma_f32_16x16x32_f16(akn[mi][0], a0, z, 0, 0, 0);
                sc[mi][jn] = __builtin_amdgcn_mfma_f32_16x16x32_f16(akn[mi][1], a1, z, 0, 0, 0);
            }
        }
        __builtin_amdgcn_s_setprio(0);

        // P(t) fragments (same-wave DS write->read ordering) + PV(t)
#pragma unroll
        for (int jn = 0; jn < 4; ++jn) {
            union { halfx8 h8; u16x4 u4[2]; } bpu;
            bpu.u4[0] = *(const u16x4*)(ps + (jn * 16 + l15) * 36 + qd * 8);
            bpu.u4[1] = *(const u16x4*)(ps + (jn * 16 + l15) * 36 + qd * 8 + 4);
            __builtin_amdgcn_s_setprio(1);
#pragma unroll
            for (int ip = 0; ip < 4; ++ip)
                o[ip][jn] = __builtin_amdgcn_mfma_f32_16x16x32_f16(avc[ip], bpu.h8, o[ip][jn], 0, 0, 0);
            __builtin_amdgcn_s_setprio(0);
        }
    }

    // finish lsum: sum across the 4 qd row-groups (keys within the strip)
#pragma unroll
    for (int jn = 0; jn < 4; ++jn) {
        float v = lsum[jn];
        v += __shfl_xor(v, 16, 64);
        v += __shfl_xor(v, 32, 64);
        lsum[jn] = v;
    }

    // ---- cross-wave sum through LDS (aliases Q+P region; both dead) ----
    float* Oacc = (float*)smem;                  // [64][68] fp32
    float* la = (float*)smem + 4352;             // [64]

    __syncthreads();
    if (wid == 0) {
#pragma unroll
        for (int jn = 0; jn < 4; ++jn) {
            int q = jn * 16 + l15;
#pragma unroll
            for (int ip = 0; ip < 4; ++ip)
                *(floatx4*)(Oacc + q * 68 + ip * 16 + qd * 4) = o[ip][jn];
            if (qd == 0) la[q] = lsum[jn];
        }
    }
    for (int w = 1; w < 4; ++w) {
        __syncthreads();
        if (wid == w) {
#pragma unroll
            for (int jn = 0; jn < 4; ++jn) {
                int q = jn * 16 + l15;
#pragma unroll
                for (int ip = 0; ip < 4; ++ip) {
                    float* p = Oacc + q * 68 + ip * 16 + qd * 4;
                    *(floatx4*)p = *(floatx4*)p + o[ip][jn];
                }
                if (qd == 0) la[q] += lsum[jn];
            }
        }
    }
    __syncthreads();

    {
        int q = tid >> 2, d0 = (tid & 3) * 16;
        float inv = __builtin_amdgcn_rcpf(la[q]);
        const float* op = Oacc + q * 68 + d0;
        u16x8 pk0, pk1;
#pragma unroll
        for (int r = 0; r < 8; ++r) pk0[r] = f2h(op[r] * inv);
#pragma unroll
        for (int r = 0; r < 8; ++r) pk1[r] = f2h(op[8 + r] * inv);
        u16* dst = attn + (size_t)(b * SEQ + q0 + q) * D_MODEL + h * DH + d0;
        *(u16x8*)dst = pk0;
        *(u16x8*)(dst + 8) = pk1;
    }
}

// ---------------- out GEMM: C[4096][768] = A * WoT^T + bias (fp32 out) ----------------
// 64x64 tile (768 blocks, 3/CU), BK=64, 4 waves each 32x32.

__global__ __launch_bounds__(256) void gemm_out(const u16* __restrict__ A, const u16* __restrict__ Bt,
                                                const float* __restrict__ bias, float* __restrict__ Cout) {
    const int tid = threadIdx.x;
    const int wid = tid >> 6;
    const int lane = tid & 63;
    const int qd = lane >> 4;
    const int l15 = lane & 15;

    const int tn = blockIdx.x * 64;
    const int tm = blockIdx.y * 64;
    const int wm = (wid >> 1) * 32;
    const int wn = (wid & 1) * 32;

    __shared__ alignas(16) u16 As[64 * 64];
    __shared__ alignas(16) u16 Bs[64 * 64];

    floatx4 acc[2][2];
#pragma unroll
    for (int i = 0; i < 2; ++i)
#pragma unroll
        for (int j = 0; j < 2; ++j) acc[i][j] = (floatx4)(0.0f);

    const u16* Ag[2];
    const u16* Bg[2];
#pragma unroll
    for (int rd = 0; rd < 2; ++rd) {
        int s = rd * 256 + tid;
        int r = s >> 3, bl = (s & 7) ^ (r & 7);
        Ag[rd] = A + (size_t)(tm + r) * 768 + bl * 8;
        Bg[rd] = Bt + (size_t)(tn + r) * 768 + bl * 8;
    }

    for (int kb = 0; kb < 768; kb += 64) {
        __syncthreads();
#pragma unroll
        for (int rd = 0; rd < 2; ++rd) {
            gload_lds16(Ag[rd] + kb, As + (size_t)(rd * 256 + tid) * 8);
            gload_lds16(Bg[rd] + kb, Bs + (size_t)(rd * 256 + tid) * 8);
        }
        __syncthreads();

#pragma unroll
        for (int ks = 0; ks < 2; ++ks) {
            halfx8 af[2], bf[2];
#pragma unroll
            for (int i = 0; i < 2; ++i) {
                int r = wm + i * 16 + l15;
                af[i] = *(const halfx8*)(As + r * 64 + (((ks * 4 + qd) ^ (r & 7)) * 8));
                int r2 = wn + i * 16 + l15;
                bf[i] = *(const halfx8*)(Bs + r2 * 64 + (((ks * 4 + qd) ^ (r2 & 7)) * 8));
            }
#pragma unroll
            for (int i = 0; i < 2; ++i)
#pragma unroll
                for (int j = 0; j < 2; ++j)
                    acc[i][j] = __builtin_amdgcn_mfma_f32_16x16x32_f16(af[i], bf[j], acc[i][j], 0, 0, 0);
        }
    }

#pragma unroll
    for (int j = 0; j < 2; ++j) {
        int col = tn + wn + j * 16 + l15;
        float bv = bias[col];
#pragma unroll
        for (int i = 0; i < 2; ++i) {
            int row0 = tm + wm + i * 16 + qd * 4;
#pragma unroll
            for (int r = 0; r < 4; ++r)
                Cout[(size_t)(row0 + r) * 768 + col] = acc[i][j][r] + bv;
        }
    }
}

// ---------------- launch ----------------

extern "C" void kernel_launch(void* const* d_in, const int* in_sizes, int n_in,
                              void* d_out, int out_size, void* d_ws, size_t ws_size,
                              hipStream_t stream) {
    const float* x  = (const float*)d_in[0];
    const float* Wq = (const float*)d_in[1];
    const float* bq = (const float*)d_in[2];
    const float* Wk = (const float*)d_in[3];
    const float* bk = (const float*)d_in[4];
    const float* Wv = (const float*)d_in[5];
    const float* bv = (const float*)d_in[6];
    const float* Wo = (const float*)d_in[7];
    const float* bo = (const float*)d_in[8];

    char* ws = (char*)d_ws;
    size_t off = 0;
    auto take = [&](size_t bytes) -> char* {
        char* p = ws + off;
        off += (bytes + 255) & ~(size_t)255;
        return p;
    };
    u16* WqkvT = (u16*)take((size_t)DQKV * D_MODEL * 2);
    u16* WoT   = (u16*)take((size_t)D_MODEL * D_MODEL * 2);
    u16* qP    = (u16*)take((size_t)MTOK * D_MODEL * 2);
    u16* kP    = (u16*)take((size_t)MTOK * D_MODEL * 2);
    u16* vTb   = (u16*)take((size_t)BATCH * NH * DH * SEQ * 2);
    u16* attn  = (u16*)take((size_t)MTOK * D_MODEL * 2);
    // xh (f16 cast of x) aliases the attn buffer: consumed by gemm_qkv before
    // attn_kernel writes it (stream-ordered).
    u16* xh = attn;

    wprep_kernel<<<576 + (MTOK * D_MODEL / 2048), 256, 0, stream>>>(Wq, Wk, Wv, Wo, x, WqkvT, WoT, xh);
    gemm_qkv<<<dim3(DQKV / 128, MTOK / 64), 256, 0, stream>>>(xh, WqkvT, bq, bk, bv, qP, kP, vTb);
    attn_kernel<<<dim3(BATCH * NH, SEQ / 64), 256, 0, stream>>>(qP, kP, vTb, attn);
    gemm_out<<<dim3(D_MODEL / 64, MTOK / 64), 256, 0, stream>>>(attn, WoT, bo, (float*)d_out);
}

// Round 4
// 185.177 us; speedup vs baseline: 1.0666x; 1.0666x over previous
//
#include <hip/hip_runtime.h>

typedef unsigned short u16;
typedef __fp16 halfx2 __attribute__((ext_vector_type(2)));
typedef __fp16 halfx8 __attribute__((ext_vector_type(8)));
typedef float floatx4 __attribute__((ext_vector_type(4)));
typedef unsigned short u16x4 __attribute__((ext_vector_type(4)));
typedef unsigned short u16x8 __attribute__((ext_vector_type(8)));

#define D_MODEL 768
#define NH 12
#define DH 64
#define SEQ 2048
#define BATCH 2
#define MTOK 4096            // BATCH*SEQ
#define DQKV 2304

__device__ __forceinline__ u16 f2h(float f) {
    __fp16 h = (__fp16)f;
    return __builtin_bit_cast(u16, h);
}

__device__ __forceinline__ void gload_lds16(const void* g, void* l) {
    __builtin_amdgcn_global_load_lds(
        (const __attribute__((address_space(1))) void*)g,
        (__attribute__((address_space(3))) void*)l, 16, 0, 0);
}

// ---------------- prep: W transposes -> f16 [n][k] (576 blocks) + x -> f16 cast (1536 blocks) ----------------

__global__ __launch_bounds__(256) void wprep_kernel(const float* __restrict__ Wq, const float* __restrict__ Wk,
                                                    const float* __restrict__ Wv, const float* __restrict__ Wo,
                                                    const float* __restrict__ x,
                                                    u16* __restrict__ WqkvT, u16* __restrict__ WoT,
                                                    u16* __restrict__ xh) {
    __shared__ u16 t[64][72];
    int bid = blockIdx.x;
    int tid = threadIdx.x;
    if (bid >= 576) {
        // x fp32 -> f16, 2048 elems per block
        int idx = (bid - 576) * 2048 + tid * 8;
        float4 v0 = *(const float4*)(x + idx);
        float4 v1 = *(const float4*)(x + idx + 4);
        union { u16x8 u; halfx2 h[4]; } pk;
        pk.h[0] = __builtin_amdgcn_cvt_pkrtz(v0.x, v0.y);
        pk.h[1] = __builtin_amdgcn_cvt_pkrtz(v0.z, v0.w);
        pk.h[2] = __builtin_amdgcn_cvt_pkrtz(v1.x, v1.y);
        pk.h[3] = __builtin_amdgcn_cvt_pkrtz(v1.z, v1.w);
        *(u16x8*)(xh + idx) = pk.u;
        return;
    }
    int z = bid / 144;
    int t2 = bid % 144;
    int k0 = (t2 / 12) * 64, n0 = (t2 % 12) * 64;
    const float* W = (z == 0) ? Wq : (z == 1) ? Wk : (z == 2) ? Wv : Wo;
    u16* dst = (z < 3) ? (WqkvT + (size_t)z * 768 * 768) : WoT;
#pragma unroll
    for (int p = 0; p < 16; ++p) {
        int idx = p * 256 + tid;
        int kr = idx >> 6, nc = idx & 63;
        t[kr][nc] = f2h(W[(size_t)(k0 + kr) * 768 + n0 + nc]);
    }
    __syncthreads();
#pragma unroll
    for (int p = 0; p < 16; ++p) {
        int idx = p * 256 + tid;
        int nr = idx >> 6, kc = idx & 63;
        dst[(size_t)(n0 + nr) * 768 + k0 + kc] = t[kc][nr];
    }
}

// ---------------- QKV GEMM, A staged from pre-cast f16 xh via global_load_lds ----------------
// 64x128 tile (1152 blocks), BK=64. Epilogue: Q -> qP[bh][s][64] pre-scaled by
// 0.125*log2e, K -> kP[bh][s][64], V -> vT[bh][d][s].

__global__ __launch_bounds__(256) void gemm_qkv(const u16* __restrict__ xh, const u16* __restrict__ Bt,
                                                const float* __restrict__ bq, const float* __restrict__ bk,
                                                const float* __restrict__ bv,
                                                u16* __restrict__ qP, u16* __restrict__ kP,
                                                u16* __restrict__ vTout) {
    const int tid = threadIdx.x;
    const int wid = tid >> 6;
    const int lane = tid & 63;
    const int qd = lane >> 4;
    const int l15 = lane & 15;

    const int tn = blockIdx.x * 128;   // 18 n-tiles
    const int tm = blockIdx.y * 64;    // 64 m-tiles
    const int wm = (wid >> 1) * 32;
    const int wn = (wid & 1) * 64;

    __shared__ alignas(16) u16 As[64 * 64];    // 8 KB
    __shared__ alignas(16) u16 Bs[128 * 64];   // 16 KB

    floatx4 acc[2][4];
#pragma unroll
    for (int i = 0; i < 2; ++i)
#pragma unroll
        for (int j = 0; j < 4; ++j) acc[i][j] = (floatx4)(0.0f);

    const u16* Ag[2];
#pragma unroll
    for (int rd = 0; rd < 2; ++rd) {
        int s = rd * 256 + tid;
        int r = s >> 3, bl = (s & 7) ^ (r & 7);
        Ag[rd] = xh + (size_t)(tm + r) * 768 + bl * 8;
    }
    const u16* Bg[4];
#pragma unroll
    for (int rd = 0; rd < 4; ++rd) {
        int s = rd * 256 + tid;
        int r = s >> 3, bl = (s & 7) ^ (r & 7);
        Bg[rd] = Bt + (size_t)(tn + r) * 768 + bl * 8;
    }

    for (int kb = 0; kb < 768; kb += 64) {
        __syncthreads();
#pragma unroll
        for (int rd = 0; rd < 2; ++rd)
            gload_lds16(Ag[rd] + kb, As + (size_t)(rd * 256 + tid) * 8);
#pragma unroll
        for (int rd = 0; rd < 4; ++rd)
            gload_lds16(Bg[rd] + kb, Bs + (size_t)(rd * 256 + tid) * 8);
        __syncthreads();

#pragma unroll
        for (int ks = 0; ks < 2; ++ks) {
            halfx8 af[2], bf[4];
#pragma unroll
            for (int i = 0; i < 2; ++i) {
                int r = wm + i * 16 + l15;
                af[i] = *(const halfx8*)(As + r * 64 + (((ks * 4 + qd) ^ (r & 7)) * 8));
            }
#pragma unroll
            for (int j = 0; j < 4; ++j) {
                int r2 = wn + j * 16 + l15;
                bf[j] = *(const halfx8*)(Bs + r2 * 64 + (((ks * 4 + qd) ^ (r2 & 7)) * 8));
            }
#pragma unroll
            for (int i = 0; i < 2; ++i)
#pragma unroll
                for (int j = 0; j < 4; ++j)
                    acc[i][j] = __builtin_amdgcn_mfma_f32_16x16x32_f16(af[i], bf[j], acc[i][j], 0, 0, 0);
        }
    }

    const float cscale = 0.125f * 1.44269504088896340736f;
    const int rgn = (tn < 768) ? 0 : (tn < 1536) ? 1 : 2;   // block-uniform
    const float* bsrc = (rgn == 0) ? bq : (rgn == 1) ? bk : bv;
#pragma unroll
    for (int j = 0; j < 4; ++j) {
        int col = tn + wn + j * 16 + l15;
        int cl = col - rgn * 768;
        float bvv = bsrc[cl];
        int h = cl >> 6, d = cl & 63;
#pragma unroll
        for (int i = 0; i < 2; ++i) {
            int row0 = tm + wm + i * 16 + qd * 4;
            int b = row0 >> 11, s0 = row0 & 2047;
            u16x4 pk;
#pragma unroll
            for (int r = 0; r < 4; ++r) {
                float v = acc[i][j][r] + bvv;
                if (rgn == 0) v *= cscale;
                pk[r] = f2h(v);
            }
            if (rgn == 2) {
                *(u16x4*)(vTout + ((size_t)(b * NH + h) * 64 + d) * SEQ + s0) = pk;
            } else {
                u16* dst = (rgn == 0) ? qP : kP;
#pragma unroll
                for (int r = 0; r < 4; ++r)
                    dst[((size_t)(b * NH + h) * SEQ + s0 + r) * DH + d] = pk[r];
            }
        }
    }
}

// ---------------- attention R15: d-split PV via shared P tile -> small accumulators, 3 blocks/CU ----------------
// grid = (24 bh, 32 q-tiles of 64) = 768 blocks at 3/CU = ONE generation (no tail).
// Per 128-key tile: each wave computes QK for its private 32-key strip (sc[2][4]),
// exp+pack -> shared P_lds[64 q][136-pad keys] (double-buffered, 1 barrier/iter),
// then each wave computes PV for its OWN 16-d slice of V across all 128 keys:
// o[4] = 16 regs (was 64). No cross-wave O reduction; only lsum is reduced.
// Peak live ~155 regs < 168 -> launch_bounds(256,3) without spills (R14 spilled
// because o[4][4] kept demand ~200). K prefetched cross-iteration (transient,
// no ping-pong copies); V loaded same-iter, consumed after the barrier.
// Race audit (1 barrier/iter, dbuf): writes to buf[c] at iter t are separated
// from buf[c]'s last readers (PV at t-2) by barrier(t-1); epilogue la4 aliases
// buf0 while last PV reads buf1 - disjoint.

__global__ __launch_bounds__(256, 3) void attn_kernel(const u16* __restrict__ qP, const u16* __restrict__ kP,
                                                      const u16* __restrict__ vT, u16* __restrict__ attn) {
    const int tid = threadIdx.x;
    const int wid = tid >> 6;
    const int lane = tid & 63;
    const int qd = lane >> 4;
    const int l15 = lane & 15;

    const int bh = blockIdx.x;
    const int b = bh / NH, h = bh % NH;
    const int q0 = blockIdx.y * 64;

    __shared__ alignas(16) u16 smem[2 * 64 * 136];   // 34816 B: double-buffered P [64 q][136]

    halfx8 aq[4][2];
#pragma unroll
    for (int jn = 0; jn < 4; ++jn)
#pragma unroll
        for (int ks = 0; ks < 2; ++ks)
            aq[jn][ks] = *(const halfx8*)(qP + (size_t)(bh * SEQ + q0 + jn * 16 + l15) * DH + ks * 32 + qd * 8);

    floatx4 o[4];
#pragma unroll
    for (int jn = 0; jn < 4; ++jn) o[jn] = (floatx4)(0.0f);
    float lsum[4] = {0.0f, 0.0f, 0.0f, 0.0f};

    const u16* kbase = kP + (size_t)(bh * SEQ + wid * 32 + l15) * DH + qd * 8;       // QK: wave's 32-key strip
    const u16* vbase = vT + (size_t)(bh * 64 + wid * 16 + l15) * SEQ + qd * 8;       // PV: wave's 16-d slice

    // prologue: K(0) + sc(0)
    floatx4 sc[2][4];
    {
        halfx8 ak0[2][2];
#pragma unroll
        for (int mi = 0; mi < 2; ++mi)
#pragma unroll
            for (int ks = 0; ks < 2; ++ks)
                ak0[mi][ks] = *(const halfx8*)(kbase + (size_t)(mi * 16) * DH + ks * 32);
#pragma unroll
        for (int jn = 0; jn < 4; ++jn) {
#pragma unroll
            for (int mi = 0; mi < 2; ++mi) {
                floatx4 z = (floatx4)(0.0f);
                z = __builtin_amdgcn_mfma_f32_16x16x32_f16(ak0[mi][0], aq[jn][0], z, 0, 0, 0);
                sc[mi][jn] = __builtin_amdgcn_mfma_f32_16x16x32_f16(ak0[mi][1], aq[jn][1], z, 0, 0, 0);
            }
        }
    }

    for (int kt = 0; kt < 16; ++kt) {
        u16* pbuf = smem + (size_t)(kt & 1) * (64 * 136);
        const int kt1 = (kt + 1) & 15;   // wrap harmless (valid addresses, last QK unused)

        // issue K(t+1) and V(t)
        halfx8 akn[2][2];
#pragma unroll
        for (int mi = 0; mi < 2; ++mi)
#pragma unroll
            for (int ks = 0; ks < 2; ++ks)
                akn[mi][ks] = *(const halfx8*)(kbase + (size_t)(kt1 * 128 + mi * 16) * DH + ks * 32);
        halfx8 avc[4];
#pragma unroll
        for (int ks = 0; ks < 4; ++ks)
            avc[ks] = *(const halfx8*)(vbase + kt * 128 + ks * 32);

        // exp(t): sc -> P (transposed layout P[q][key]), lsum on VALU. sc dead after.
#pragma unroll
        for (int mi = 0; mi < 2; ++mi)
#pragma unroll
            for (int jn = 0; jn < 4; ++jn) {
                float p0 = __builtin_amdgcn_exp2f(sc[mi][jn][0]);
                float p1 = __builtin_amdgcn_exp2f(sc[mi][jn][1]);
                float p2 = __builtin_amdgcn_exp2f(sc[mi][jn][2]);
                float p3 = __builtin_amdgcn_exp2f(sc[mi][jn][3]);
                lsum[jn] += (p0 + p1) + (p2 + p3);
                union { u16x4 u; halfx2 h[2]; } pk;
                pk.h[0] = __builtin_amdgcn_cvt_pkrtz(p0, p1);
                pk.h[1] = __builtin_amdgcn_cvt_pkrtz(p2, p3);
                *(u16x4*)(pbuf + (jn * 16 + l15) * 136 + wid * 32 + mi * 16 + qd * 4) = pk.u;
            }

        // QK(t+1): overwrite sc in place (overlaps other waves' exp)
        __builtin_amdgcn_s_setprio(1);
#pragma unroll
        for (int jn = 0; jn < 4; ++jn) {
#pragma unroll
            for (int mi = 0; mi < 2; ++mi) {
                floatx4 z = (floatx4)(0.0f);
                z = __builtin_amdgcn_mfma_f32_16x16x32_f16(akn[mi][0], aq[jn][0], z, 0, 0, 0);
                sc[mi][jn] = __builtin_amdgcn_mfma_f32_16x16x32_f16(akn[mi][1], aq[jn][1], z, 0, 0, 0);
            }
        }
        __builtin_amdgcn_s_setprio(0);

        __syncthreads();   // P(t) complete across waves

        // PV(t): wave's 16-d V slice x all 128 keys of the tile
        __builtin_amdgcn_s_setprio(1);
#pragma unroll
        for (int ks = 0; ks < 4; ++ks) {
#pragma unroll
            for (int jn = 0; jn < 4; ++jn) {
                halfx8 bp = *(const halfx8*)(pbuf + (jn * 16 + l15) * 136 + ks * 32 + qd * 8);
                o[jn] = __builtin_amdgcn_mfma_f32_16x16x32_f16(avc[ks], bp, o[jn], 0, 0, 0);
            }
        }
        __builtin_amdgcn_s_setprio(0);
    }

    // lsum: reduce over qd groups (keys within strip), then across waves via LDS
#pragma unroll
    for (int jn = 0; jn < 4; ++jn) {
        float v = lsum[jn];
        v += __shfl_xor(v, 16, 64);
        v += __shfl_xor(v, 32, 64);
        lsum[jn] = v;
    }

    float* la4 = (float*)smem;   // aliases buf0 (free: last PV reads buf1; buf0 readers pre-barrier(15))
    if (qd == 0) {
#pragma unroll
        for (int jn = 0; jn < 4; ++jn)
            la4[wid * 64 + jn * 16 + l15] = lsum[jn];
    }
    __syncthreads();

#pragma unroll
    for (int jn = 0; jn < 4; ++jn) {
        int q = jn * 16 + l15;
        float s = (la4[q] + la4[64 + q]) + (la4[128 + q] + la4[192 + q]);
        float inv = __builtin_amdgcn_rcpf(s);
        u16x4 pk;
#pragma unroll
        for (int r = 0; r < 4; ++r) pk[r] = f2h(o[jn][r] * inv);
        u16* dst = attn + (size_t)(b * SEQ + q0 + q) * D_MODEL + h * DH + wid * 16 + qd * 4;
        *(u16x4*)dst = pk;
    }
}

// ---------------- out GEMM: C[4096][768] = A * WoT^T + bias (fp32 out) ----------------
// 64x64 tile (768 blocks, 3/CU), BK=64, 4 waves each 32x32.

__global__ __launch_bounds__(256) void gemm_out(const u16* __restrict__ A, const u16* __restrict__ Bt,
                                                const float* __restrict__ bias, float* __restrict__ Cout) {
    const int tid = threadIdx.x;
    const int wid = tid >> 6;
    const int lane = tid & 63;
    const int qd = lane >> 4;
    const int l15 = lane & 15;

    const int tn = blockIdx.x * 64;
    const int tm = blockIdx.y * 64;
    const int wm = (wid >> 1) * 32;
    const int wn = (wid & 1) * 32;

    __shared__ alignas(16) u16 As[64 * 64];
    __shared__ alignas(16) u16 Bs[64 * 64];

    floatx4 acc[2][2];
#pragma unroll
    for (int i = 0; i < 2; ++i)
#pragma unroll
        for (int j = 0; j < 2; ++j) acc[i][j] = (floatx4)(0.0f);

    const u16* Ag[2];
    const u16* Bg[2];
#pragma unroll
    for (int rd = 0; rd < 2; ++rd) {
        int s = rd * 256 + tid;
        int r = s >> 3, bl = (s & 7) ^ (r & 7);
        Ag[rd] = A + (size_t)(tm + r) * 768 + bl * 8;
        Bg[rd] = Bt + (size_t)(tn + r) * 768 + bl * 8;
    }

    for (int kb = 0; kb < 768; kb += 64) {
        __syncthreads();
#pragma unroll
        for (int rd = 0; rd < 2; ++rd) {
            gload_lds16(Ag[rd] + kb, As + (size_t)(rd * 256 + tid) * 8);
            gload_lds16(Bg[rd] + kb, Bs + (size_t)(rd * 256 + tid) * 8);
        }
        __syncthreads();

#pragma unroll
        for (int ks = 0; ks < 2; ++ks) {
            halfx8 af[2], bf[2];
#pragma unroll
            for (int i = 0; i < 2; ++i) {
                int r = wm + i * 16 + l15;
                af[i] = *(const halfx8*)(As + r * 64 + (((ks * 4 + qd) ^ (r & 7)) * 8));
                int r2 = wn + i * 16 + l15;
                bf[i] = *(const halfx8*)(Bs + r2 * 64 + (((ks * 4 + qd) ^ (r2 & 7)) * 8));
            }
#pragma unroll
            for (int i = 0; i < 2; ++i)
#pragma unroll
                for (int j = 0; j < 2; ++j)
                    acc[i][j] = __builtin_amdgcn_mfma_f32_16x16x32_f16(af[i], bf[j], acc[i][j], 0, 0, 0);
        }
    }

#pragma unroll
    for (int j = 0; j < 2; ++j) {
        int col = tn + wn + j * 16 + l15;
        float bv = bias[col];
#pragma unroll
        for (int i = 0; i < 2; ++i) {
            int row0 = tm + wm + i * 16 + qd * 4;
#pragma unroll
            for (int r = 0; r < 4; ++r)
                Cout[(size_t)(row0 + r) * 768 + col] = acc[i][j][r] + bv;
        }
    }
}

// ---------------- launch ----------------

extern "C" void kernel_launch(void* const* d_in, const int* in_sizes, int n_in,
                              void* d_out, int out_size, void* d_ws, size_t ws_size,
                              hipStream_t stream) {
    const float* x  = (const float*)d_in[0];
    const float* Wq = (const float*)d_in[1];
    const float* bq = (const float*)d_in[2];
    const float* Wk = (const float*)d_in[3];
    const float* bk = (const float*)d_in[4];
    const float* Wv = (const float*)d_in[5];
    const float* bv = (const float*)d_in[6];
    const float* Wo = (const float*)d_in[7];
    const float* bo = (const float*)d_in[8];

    char* ws = (char*)d_ws;
    size_t off = 0;
    auto take = [&](size_t bytes) -> char* {
        char* p = ws + off;
        off += (bytes + 255) & ~(size_t)255;
        return p;
    };
    u16* WqkvT = (u16*)take((size_t)DQKV * D_MODEL * 2);
    u16* WoT   = (u16*)take((size_t)D_MODEL * D_MODEL * 2);
    u16* qP    = (u16*)take((size_t)MTOK * D_MODEL * 2);
    u16* kP    = (u16*)take((size_t)MTOK * D_MODEL * 2);
    u16* vTb   = (u16*)take((size_t)BATCH * NH * DH * SEQ * 2);
    u16* attn  = (u16*)take((size_t)MTOK * D_MODEL * 2);
    // xh (f16 cast of x) aliases the attn buffer: consumed by gemm_qkv before
    // attn_kernel writes it (stream-ordered).
    u16* xh = attn;

    wprep_kernel<<<576 + (MTOK * D_MODEL / 2048), 256, 0, stream>>>(Wq, Wk, Wv, Wo, x, WqkvT, WoT, xh);
    gemm_qkv<<<dim3(DQKV / 128, MTOK / 64), 256, 0, stream>>>(xh, WqkvT, bq, bk, bv, qP, kP, vTb);
    attn_kernel<<<dim3(BATCH * NH, SEQ / 64), 256, 0, stream>>>(qP, kP, vTb, attn);
    gemm_out<<<dim3(D_MODEL / 64, MTOK / 64), 256, 0, stream>>>(attn, WoT, bo, (float*)d_out);
}

// Round 5
// 179.479 us; speedup vs baseline: 1.1005x; 1.0317x over previous
//
#include <hip/hip_runtime.h>

typedef unsigned short u16;
typedef __fp16 halfx2 __attribute__((ext_vector_type(2)));
typedef __fp16 halfx8 __attribute__((ext_vector_type(8)));
typedef float floatx4 __attribute__((ext_vector_type(4)));
typedef unsigned short u16x4 __attribute__((ext_vector_type(4)));
typedef unsigned short u16x8 __attribute__((ext_vector_type(8)));

#define D_MODEL 768
#define NH 12
#define DH 64
#define SEQ 2048
#define BATCH 2
#define MTOK 4096            // BATCH*SEQ
#define DQKV 2304

__device__ __forceinline__ u16 f2h(float f) {
    __fp16 h = (__fp16)f;
    return __builtin_bit_cast(u16, h);
}

__device__ __forceinline__ void gload_lds16(const void* g, void* l) {
    __builtin_amdgcn_global_load_lds(
        (const __attribute__((address_space(1))) void*)g,
        (__attribute__((address_space(3))) void*)l, 16, 0, 0);
}

// ---------------- prep: W transposes -> f16 [n][k] (576 blocks) + x -> f16 cast (1536 blocks) ----------------

__global__ __launch_bounds__(256) void wprep_kernel(const float* __restrict__ Wq, const float* __restrict__ Wk,
                                                    const float* __restrict__ Wv, const float* __restrict__ Wo,
                                                    const float* __restrict__ x,
                                                    u16* __restrict__ WqkvT, u16* __restrict__ WoT,
                                                    u16* __restrict__ xh) {
    __shared__ u16 t[64][72];
    int bid = blockIdx.x;
    int tid = threadIdx.x;
    if (bid >= 576) {
        // x fp32 -> f16, 2048 elems per block
        int idx = (bid - 576) * 2048 + tid * 8;
        float4 v0 = *(const float4*)(x + idx);
        float4 v1 = *(const float4*)(x + idx + 4);
        union { u16x8 u; halfx2 h[4]; } pk;
        pk.h[0] = __builtin_amdgcn_cvt_pkrtz(v0.x, v0.y);
        pk.h[1] = __builtin_amdgcn_cvt_pkrtz(v0.z, v0.w);
        pk.h[2] = __builtin_amdgcn_cvt_pkrtz(v1.x, v1.y);
        pk.h[3] = __builtin_amdgcn_cvt_pkrtz(v1.z, v1.w);
        *(u16x8*)(xh + idx) = pk.u;
        return;
    }
    int z = bid / 144;
    int t2 = bid % 144;
    int k0 = (t2 / 12) * 64, n0 = (t2 % 12) * 64;
    const float* W = (z == 0) ? Wq : (z == 1) ? Wk : (z == 2) ? Wv : Wo;
    u16* dst = (z < 3) ? (WqkvT + (size_t)z * 768 * 768) : WoT;
#pragma unroll
    for (int p = 0; p < 16; ++p) {
        int idx = p * 256 + tid;
        int kr = idx >> 6, nc = idx & 63;
        t[kr][nc] = f2h(W[(size_t)(k0 + kr) * 768 + n0 + nc]);
    }
    __syncthreads();
#pragma unroll
    for (int p = 0; p < 16; ++p) {
        int idx = p * 256 + tid;
        int nr = idx >> 6, kc = idx & 63;
        dst[(size_t)(n0 + nr) * 768 + k0 + kc] = t[kc][nr];
    }
}

// ---------------- QKV GEMM, A staged from pre-cast f16 xh via global_load_lds ----------------
// 64x128 tile (1152 blocks), BK=64. Epilogue: Q -> qP[bh][s][64] pre-scaled by
// 0.125*log2e, K -> kP[bh][s][64], V -> vT[bh][d][s].

__global__ __launch_bounds__(256) void gemm_qkv(const u16* __restrict__ xh, const u16* __restrict__ Bt,
                                                const float* __restrict__ bq, const float* __restrict__ bk,
                                                const float* __restrict__ bv,
                                                u16* __restrict__ qP, u16* __restrict__ kP,
                                                u16* __restrict__ vTout) {
    const int tid = threadIdx.x;
    const int wid = tid >> 6;
    const int lane = tid & 63;
    const int qd = lane >> 4;
    const int l15 = lane & 15;

    const int tn = blockIdx.x * 128;   // 18 n-tiles
    const int tm = blockIdx.y * 64;    // 64 m-tiles
    const int wm = (wid >> 1) * 32;
    const int wn = (wid & 1) * 64;

    __shared__ alignas(16) u16 As[64 * 64];    // 8 KB
    __shared__ alignas(16) u16 Bs[128 * 64];   // 16 KB

    floatx4 acc[2][4];
#pragma unroll
    for (int i = 0; i < 2; ++i)
#pragma unroll
        for (int j = 0; j < 4; ++j) acc[i][j] = (floatx4)(0.0f);

    const u16* Ag[2];
#pragma unroll
    for (int rd = 0; rd < 2; ++rd) {
        int s = rd * 256 + tid;
        int r = s >> 3, bl = (s & 7) ^ (r & 7);
        Ag[rd] = xh + (size_t)(tm + r) * 768 + bl * 8;
    }
    const u16* Bg[4];
#pragma unroll
    for (int rd = 0; rd < 4; ++rd) {
        int s = rd * 256 + tid;
        int r = s >> 3, bl = (s & 7) ^ (r & 7);
        Bg[rd] = Bt + (size_t)(tn + r) * 768 + bl * 8;
    }

    for (int kb = 0; kb < 768; kb += 64) {
        __syncthreads();
#pragma unroll
        for (int rd = 0; rd < 2; ++rd)
            gload_lds16(Ag[rd] + kb, As + (size_t)(rd * 256 + tid) * 8);
#pragma unroll
        for (int rd = 0; rd < 4; ++rd)
            gload_lds16(Bg[rd] + kb, Bs + (size_t)(rd * 256 + tid) * 8);
        __syncthreads();

#pragma unroll
        for (int ks = 0; ks < 2; ++ks) {
            halfx8 af[2], bf[4];
#pragma unroll
            for (int i = 0; i < 2; ++i) {
                int r = wm + i * 16 + l15;
                af[i] = *(const halfx8*)(As + r * 64 + (((ks * 4 + qd) ^ (r & 7)) * 8));
            }
#pragma unroll
            for (int j = 0; j < 4; ++j) {
                int r2 = wn + j * 16 + l15;
                bf[j] = *(const halfx8*)(Bs + r2 * 64 + (((ks * 4 + qd) ^ (r2 & 7)) * 8));
            }
#pragma unroll
            for (int i = 0; i < 2; ++i)
#pragma unroll
                for (int j = 0; j < 4; ++j)
                    acc[i][j] = __builtin_amdgcn_mfma_f32_16x16x32_f16(af[i], bf[j], acc[i][j], 0, 0, 0);
        }
    }

    const float cscale = 0.125f * 1.44269504088896340736f;
    const int rgn = (tn < 768) ? 0 : (tn < 1536) ? 1 : 2;   // block-uniform
    const float* bsrc = (rgn == 0) ? bq : (rgn == 1) ? bk : bv;
#pragma unroll
    for (int j = 0; j < 4; ++j) {
        int col = tn + wn + j * 16 + l15;
        int cl = col - rgn * 768;
        float bvv = bsrc[cl];
        int h = cl >> 6, d = cl & 63;
#pragma unroll
        for (int i = 0; i < 2; ++i) {
            int row0 = tm + wm + i * 16 + qd * 4;
            int b = row0 >> 11, s0 = row0 & 2047;
            u16x4 pk;
#pragma unroll
            for (int r = 0; r < 4; ++r) {
                float v = acc[i][j][r] + bvv;
                if (rgn == 0) v *= cscale;
                pk[r] = f2h(v);
            }
            if (rgn == 2) {
                *(u16x4*)(vTout + ((size_t)(b * NH + h) * 64 + d) * SEQ + s0) = pk;
            } else {
                u16* dst = (rgn == 0) ? qP : kP;
#pragma unroll
                for (int r = 0; r < 4; ++r)
                    dst[((size_t)(b * NH + h) * SEQ + s0 + r) * DH + d] = pk[r];
            }
        }
    }
}

// ---------------- attention R16: swizzled P tile + 2x2 (d-half, k-half) PV split ----------------
// grid = (24 bh, 32 q-tiles of 64) = 768 blocks at 3/CU (one generation).
// QK: each wave computes its private 32-key strip (as R15). P stored in a
// pad-free [64 q][128 k] tile with 16B-chunk XOR swizzle (chunk ^= qrow&7):
// rows are bank-aligned, writes/reads both hit the 32-bank minimum (R15's
// 136-u16 pad gave bank-advance-4 rows -> 4.7M conflict cycles, 32x R13).
// PV: wave = (dh = wid>>1, kh = wid&1) computes its 32-d half x its 64-key
// half: o[2][4] = 32 regs, and P reads drop to 8 KB/iter/wave (R15 read the
// full 16 KB tile per wave). Epilogue: kh=1 stores o to LDS fp32 [2][64][33],
// kh=0 adds, normalizes by the 4-wave lsum, stores. ~156 live regs -> (256,3)
// without spills. Double-buffered P, 1 barrier/iter (same race audit as R15).

__global__ __launch_bounds__(256, 3) void attn_kernel(const u16* __restrict__ qP, const u16* __restrict__ kP,
                                                      const u16* __restrict__ vT, u16* __restrict__ attn) {
    const int tid = threadIdx.x;
    const int wid = tid >> 6;
    const int lane = tid & 63;
    const int qd = lane >> 4;
    const int l15 = lane & 15;
    const int r7 = l15 & 7;
    const int dh = wid >> 1, kh = wid & 1;

    const int bh = blockIdx.x;
    const int b = bh / NH, h = bh % NH;
    const int q0 = blockIdx.y * 64;

    __shared__ alignas(16) u16 smem[2 * 64 * 128];   // 32 KB: double-buffered P [64 q][128 k], swizzled

    halfx8 aq[4][2];
#pragma unroll
    for (int jn = 0; jn < 4; ++jn)
#pragma unroll
        for (int ks = 0; ks < 2; ++ks)
            aq[jn][ks] = *(const halfx8*)(qP + (size_t)(bh * SEQ + q0 + jn * 16 + l15) * DH + ks * 32 + qd * 8);

    floatx4 o[2][4];
#pragma unroll
    for (int ip = 0; ip < 2; ++ip)
#pragma unroll
        for (int jn = 0; jn < 4; ++jn) o[ip][jn] = (floatx4)(0.0f);
    float lsum[4] = {0.0f, 0.0f, 0.0f, 0.0f};

    const u16* kbase = kP + (size_t)(bh * SEQ + wid * 32 + l15) * DH + qd * 8;                 // QK: wave's 32-key strip
    const u16* vbase = vT + (size_t)(bh * 64 + dh * 32 + l15) * SEQ + kh * 64 + qd * 8;       // PV: 32-d half, 64-key half

    // prologue: K(0) + sc(0)
    floatx4 sc[2][4];
    {
        halfx8 ak0[2][2];
#pragma unroll
        for (int mi = 0; mi < 2; ++mi)
#pragma unroll
            for (int ks = 0; ks < 2; ++ks)
                ak0[mi][ks] = *(const halfx8*)(kbase + (size_t)(mi * 16) * DH + ks * 32);
#pragma unroll
        for (int jn = 0; jn < 4; ++jn) {
#pragma unroll
            for (int mi = 0; mi < 2; ++mi) {
                floatx4 z = (floatx4)(0.0f);
                z = __builtin_amdgcn_mfma_f32_16x16x32_f16(ak0[mi][0], aq[jn][0], z, 0, 0, 0);
                sc[mi][jn] = __builtin_amdgcn_mfma_f32_16x16x32_f16(ak0[mi][1], aq[jn][1], z, 0, 0, 0);
            }
        }
    }

    for (int kt = 0; kt < 16; ++kt) {
        u16* pbuf = smem + (size_t)(kt & 1) * (64 * 128);
        const int kt1 = (kt + 1) & 15;   // wrap harmless (valid addresses, last QK unused)

        // issue K(t+1) and V(t)
        halfx8 akn[2][2];
#pragma unroll
        for (int mi = 0; mi < 2; ++mi)
#pragma unroll
            for (int ks = 0; ks < 2; ++ks)
                akn[mi][ks] = *(const halfx8*)(kbase + (size_t)(kt1 * 128 + mi * 16) * DH + ks * 32);
        halfx8 avc[2][2];
#pragma unroll
        for (int ip = 0; ip < 2; ++ip)
#pragma unroll
            for (int ks = 0; ks < 2; ++ks)
                avc[ip][ks] = *(const halfx8*)(vbase + (size_t)(ip * 16) * SEQ + kt * 128 + ks * 32);

        // exp(t): sc -> swizzled P[q][k], lsum on VALU. sc dead after.
        // write key k = wid*32 + mi*16 + qd*4 : chunk16 = wid*4+mi*2+(qd>>1), sub = (qd&1)*4
#pragma unroll
        for (int mi = 0; mi < 2; ++mi)
#pragma unroll
            for (int jn = 0; jn < 4; ++jn) {
                float p0 = __builtin_amdgcn_exp2f(sc[mi][jn][0]);
                float p1 = __builtin_amdgcn_exp2f(sc[mi][jn][1]);
                float p2 = __builtin_amdgcn_exp2f(sc[mi][jn][2]);
                float p3 = __builtin_amdgcn_exp2f(sc[mi][jn][3]);
                lsum[jn] += (p0 + p1) + (p2 + p3);
                union { u16x4 u; halfx2 h[2]; } pk;
                pk.h[0] = __builtin_amdgcn_cvt_pkrtz(p0, p1);
                pk.h[1] = __builtin_amdgcn_cvt_pkrtz(p2, p3);
                *(u16x4*)(pbuf + (jn * 16 + l15) * 128 +
                          ((wid * 4 + mi * 2 + (qd >> 1)) ^ r7) * 8 + (qd & 1) * 4) = pk.u;
            }

        // QK(t+1): overwrite sc in place (overlaps other waves' exp)
        __builtin_amdgcn_s_setprio(1);
#pragma unroll
        for (int jn = 0; jn < 4; ++jn) {
#pragma unroll
            for (int mi = 0; mi < 2; ++mi) {
                floatx4 z = (floatx4)(0.0f);
                z = __builtin_amdgcn_mfma_f32_16x16x32_f16(akn[mi][0], aq[jn][0], z, 0, 0, 0);
                sc[mi][jn] = __builtin_amdgcn_mfma_f32_16x16x32_f16(akn[mi][1], aq[jn][1], z, 0, 0, 0);
            }
        }
        __builtin_amdgcn_s_setprio(0);

        __syncthreads();   // P(t) complete across waves

        // PV(t): 32-d half x 64-key half; read k = kh*64+ks*32+qd*8 : chunk16 = kh*8+ks*4+qd
        __builtin_amdgcn_s_setprio(1);
#pragma unroll
        for (int ks = 0; ks < 2; ++ks) {
#pragma unroll
            for (int jn = 0; jn < 4; ++jn) {
                halfx8 bp = *(const halfx8*)(pbuf + (jn * 16 + l15) * 128 +
                                             ((kh * 8 + ks * 4 + qd) ^ r7) * 8);
#pragma unroll
                for (int ip = 0; ip < 2; ++ip)
                    o[ip][jn] = __builtin_amdgcn_mfma_f32_16x16x32_f16(avc[ip][ks], bp, o[ip][jn], 0, 0, 0);
            }
        }
        __builtin_amdgcn_s_setprio(0);
    }

    // lsum: reduce over qd groups (keys within strip)
#pragma unroll
    for (int jn = 0; jn < 4; ++jn) {
        float v = lsum[jn];
        v += __shfl_xor(v, 16, 64);
        v += __shfl_xor(v, 32, 64);
        lsum[jn] = v;
    }

    __syncthreads();   // all PV(15) reads of buf1 done; smem reusable

    float* obuf = (float*)smem;              // [2 dh][64 q][33] fp32 = 4224 floats
    float* la4  = (float*)smem + 4352;       // [4 wid][64 q]

    if (kh == 1) {
#pragma unroll
        for (int jn = 0; jn < 4; ++jn)
#pragma unroll
            for (int ip = 0; ip < 2; ++ip)
                *(floatx4*)(obuf + (size_t)(dh * 64 + jn * 16 + l15) * 33 + ip * 16 + qd * 4) = o[ip][jn];
    }
    if (qd == 0) {
#pragma unroll
        for (int jn = 0; jn < 4; ++jn)
            la4[wid * 64 + jn * 16 + l15] = lsum[jn];
    }
    __syncthreads();

    if (kh == 0) {
#pragma unroll
        for (int jn = 0; jn < 4; ++jn) {
            int q = jn * 16 + l15;
            float s = (la4[q] + la4[64 + q]) + (la4[128 + q] + la4[192 + q]);
            float inv = __builtin_amdgcn_rcpf(s);
#pragma unroll
            for (int ip = 0; ip < 2; ++ip) {
                floatx4 val = o[ip][jn] + *(const floatx4*)(obuf + (size_t)(dh * 64 + q) * 33 + ip * 16 + qd * 4);
                u16x4 pk;
#pragma unroll
                for (int r = 0; r < 4; ++r) pk[r] = f2h(val[r] * inv);
                *(u16x4*)(attn + (size_t)(b * SEQ + q0 + q) * D_MODEL + h * DH + dh * 32 + ip * 16 + qd * 4) = pk;
            }
        }
    }
}

// ---------------- out GEMM: C[4096][768] = A * WoT^T + bias (fp32 out) ----------------
// 64x64 tile (768 blocks, 3/CU), BK=64, 4 waves each 32x32.

__global__ __launch_bounds__(256) void gemm_out(const u16* __restrict__ A, const u16* __restrict__ Bt,
                                                const float* __restrict__ bias, float* __restrict__ Cout) {
    const int tid = threadIdx.x;
    const int wid = tid >> 6;
    const int lane = tid & 63;
    const int qd = lane >> 4;
    const int l15 = lane & 15;

    const int tn = blockIdx.x * 64;
    const int tm = blockIdx.y * 64;
    const int wm = (wid >> 1) * 32;
    const int wn = (wid & 1) * 32;

    __shared__ alignas(16) u16 As[64 * 64];
    __shared__ alignas(16) u16 Bs[64 * 64];

    floatx4 acc[2][2];
#pragma unroll
    for (int i = 0; i < 2; ++i)
#pragma unroll
        for (int j = 0; j < 2; ++j) acc[i][j] = (floatx4)(0.0f);

    const u16* Ag[2];
    const u16* Bg[2];
#pragma unroll
    for (int rd = 0; rd < 2; ++rd) {
        int s = rd * 256 + tid;
        int r = s >> 3, bl = (s & 7) ^ (r & 7);
        Ag[rd] = A + (size_t)(tm + r) * 768 + bl * 8;
        Bg[rd] = Bt + (size_t)(tn + r) * 768 + bl * 8;
    }

    for (int kb = 0; kb < 768; kb += 64) {
        __syncthreads();
#pragma unroll
        for (int rd = 0; rd < 2; ++rd) {
            gload_lds16(Ag[rd] + kb, As + (size_t)(rd * 256 + tid) * 8);
            gload_lds16(Bg[rd] + kb, Bs + (size_t)(rd * 256 + tid) * 8);
        }
        __syncthreads();

#pragma unroll
        for (int ks = 0; ks < 2; ++ks) {
            halfx8 af[2], bf[2];
#pragma unroll
            for (int i = 0; i < 2; ++i) {
                int r = wm + i * 16 + l15;
                af[i] = *(const halfx8*)(As + r * 64 + (((ks * 4 + qd) ^ (r & 7)) * 8));
                int r2 = wn + i * 16 + l15;
                bf[i] = *(const halfx8*)(Bs + r2 * 64 + (((ks * 4 + qd) ^ (r2 & 7)) * 8));
            }
#pragma unroll
            for (int i = 0; i < 2; ++i)
#pragma unroll
                for (int j = 0; j < 2; ++j)
                    acc[i][j] = __builtin_amdgcn_mfma_f32_16x16x32_f16(af[i], bf[j], acc[i][j], 0, 0, 0);
        }
    }

#pragma unroll
    for (int j = 0; j < 2; ++j) {
        int col = tn + wn + j * 16 + l15;
        float bv = bias[col];
#pragma unroll
        for (int i = 0; i < 2; ++i) {
            int row0 = tm + wm + i * 16 + qd * 4;
#pragma unroll
            for (int r = 0; r < 4; ++r)
                Cout[(size_t)(row0 + r) * 768 + col] = acc[i][j][r] + bv;
        }
    }
}

// ---------------- launch ----------------

extern "C" void kernel_launch(void* const* d_in, const int* in_sizes, int n_in,
                              void* d_out, int out_size, void* d_ws, size_t ws_size,
                              hipStream_t stream) {
    const float* x  = (const float*)d_in[0];
    const float* Wq = (const float*)d_in[1];
    const float* bq = (const float*)d_in[2];
    const float* Wk = (const float*)d_in[3];
    const float* bk = (const float*)d_in[4];
    const float* Wv = (const float*)d_in[5];
    const float* bv = (const float*)d_in[6];
    const float* Wo = (const float*)d_in[7];
    const float* bo = (const float*)d_in[8];

    char* ws = (char*)d_ws;
    size_t off = 0;
    auto take = [&](size_t bytes) -> char* {
        char* p = ws + off;
        off += (bytes + 255) & ~(size_t)255;
        return p;
    };
    u16* WqkvT = (u16*)take((size_t)DQKV * D_MODEL * 2);
    u16* WoT   = (u16*)take((size_t)D_MODEL * D_MODEL * 2);
    u16* qP    = (u16*)take((size_t)MTOK * D_MODEL * 2);
    u16* kP    = (u16*)take((size_t)MTOK * D_MODEL * 2);
    u16* vTb   = (u16*)take((size_t)BATCH * NH * DH * SEQ * 2);
    u16* attn  = (u16*)take((size_t)MTOK * D_MODEL * 2);
    // xh (f16 cast of x) aliases the attn buffer: consumed by gemm_qkv before
    // attn_kernel writes it (stream-ordered).
    u16* xh = attn;

    wprep_kernel<<<576 + (MTOK * D_MODEL / 2048), 256, 0, stream>>>(Wq, Wk, Wv, Wo, x, WqkvT, WoT, xh);
    gemm_qkv<<<dim3(DQKV / 128, MTOK / 64), 256, 0, stream>>>(xh, WqkvT, bq, bk, bv, qP, kP, vTb);
    attn_kernel<<<dim3(BATCH * NH, SEQ / 64), 256, 0, stream>>>(qP, kP, vTb, attn);
    gemm_out<<<dim3(D_MODEL / 64, MTOK / 64), 256, 0, stream>>>(attn, WoT, bo, (float*)d_out);
}